// Round 3
// baseline (7061.758 us; speedup 1.0000x reference)
//
#include <hip/hip_runtime.h>
#include <hip/hip_bf16.h>

// Problem dims
#define SS 256
#define BB 512
#define II 46
#define HH 256
#define CC 40
#define SB (SS*BB)        // 131072 rows
#define G3 (3*HH)         // 768
#define EPSF 1e-5f

typedef __attribute__((ext_vector_type(8))) short bf16x8;
typedef __attribute__((ext_vector_type(4))) float f32x4;

// ---------------------------------------------------------------------------
// helpers
// ---------------------------------------------------------------------------
__device__ __forceinline__ unsigned short f2bf_rne(float f){
  unsigned u = __float_as_uint(f);
  unsigned r = (u + 0x7FFFu + ((u >> 16) & 1u)) >> 16;
  return (unsigned short)r;
}
__device__ __forceinline__ float bf2f(unsigned short b){
  return __uint_as_float(((unsigned)b) << 16);
}
__device__ __forceinline__ void cvt8(const float* v, bf16x8& hi, bf16x8& lo){
  #pragma unroll
  for (int e=0;e<8;e++){
    unsigned short hb = f2bf_rne(v[e]);
    hi[e] = (short)hb;
    lo[e] = (short)f2bf_rne(v[e] - bf2f(hb));
  }
}

// ---------------------------------------------------------------------------
// pack XM chunk = [Xin | Min]  (Rr x 80) from X,M rows [r0, r0+Rr)
// (pass A only now — Xc persisted afterwards)
// ---------------------------------------------------------------------------
__global__ void pack_xm_chunk_k(const float* __restrict__ X, const float* __restrict__ Mi,
                                float* __restrict__ XM, long long r0, int Rr){
  long long idx = (long long)blockIdx.x*blockDim.x + threadIdx.x;
  if (idx >= (long long)Rr*80) return;
  int r = (int)(idx / 80);
  int c = (int)(idx - (long long)r*80);
  long long gr = r0 + r;
  float v;
  if (c < CC) v = X[gr*II + c];
  else        v = Mi[gr*II + (c - CC)];
  XM[idx] = v;
}

// ---------------------------------------------------------------------------
// h0[b,j] = sum_{c<6} X[0,b,40+c] * i2h_w[j,c] + i2h_b[j]  -> both carries
// ---------------------------------------------------------------------------
__global__ void h0_k(const float* __restrict__ X, const float* __restrict__ w,
                     const float* __restrict__ bias, float* __restrict__ h1c,
                     float* __restrict__ h2c){
  int b = blockIdx.x, jj = threadIdx.x;
  const float* p = X + (long long)b*II + (II - 6);
  float acc = bias[jj];
  #pragma unroll
  for (int c2=0;c2<6;c2++) acc = fmaf(p[c2], w[jj*6 + c2], acc);
  h1c[(long long)b*HH + jj] = acc;
  h2c[(long long)b*HH + jj] = acc;
}

// ---------------------------------------------------------------------------
// transpose whh (768x256) -> whhT (256x768), once per launch
// ---------------------------------------------------------------------------
__global__ void whht_k(const float* __restrict__ w, float* __restrict__ wt){
  int idx = blockIdx.x*blockDim.x + threadIdx.x;
  if (idx >= G3*HH) return;
  int u = idx / HH, k = idx - u*HH;      // w[u][k]
  wt[(size_t)k*G3 + u] = w[idx];
}

// ---------------------------------------------------------------------------
// Generic f32 GEMM (small-K ops only: comb K=80, down/conv1 K=40).
// MODE 0: store; MODE 1: store relu; MODE 2: accumulate
// ---------------------------------------------------------------------------
template<int MODE>
__global__ void gemm_tn(const float* __restrict__ A, int lda,
                        const float* __restrict__ W, int ldw,
                        const float* __restrict__ bias,
                        float* __restrict__ Co, int ldc,
                        int Mrows, int N, int K)
{
  __shared__ __align__(16) float As[32][132];
  __shared__ __align__(16) float Ws[32][132];
  const int m0 = blockIdx.x*128, n0 = blockIdx.y*128;
  const int t  = threadIdx.x;
  const int tm = t >> 4, tn = t & 15;
  float acc[8][8];
  #pragma unroll
  for (int i=0;i<8;i++)
    #pragma unroll
    for (int j2=0;j2<8;j2++) acc[i][j2] = 0.f;

  for (int k0=0;k0<K;k0+=32){
    #pragma unroll
    for (int u=0;u<16;u++){
      int idx = u*256 + t;
      int r = idx >> 5, c = idx & 31;
      int gk = k0 + c;
      float av = 0.f, wv = 0.f;
      if (gk < K){
        int gm = m0 + r;
        if (gm < Mrows) av = A[(long long)gm*lda + gk];
        int gn = n0 + r;
        if (gn < N)     wv = W[(long long)gn*ldw + gk];
      }
      As[c][r] = av;
      Ws[c][r] = wv;
    }
    __syncthreads();
    #pragma unroll
    for (int kk=0;kk<32;kk++){
      const float4 a0 = *(const float4*)&As[kk][tm*8];
      const float4 a1 = *(const float4*)&As[kk][tm*8+4];
      const float4 b0 = *(const float4*)&Ws[kk][tn*8];
      const float4 b1 = *(const float4*)&Ws[kk][tn*8+4];
      const float av[8] = {a0.x,a0.y,a0.z,a0.w,a1.x,a1.y,a1.z,a1.w};
      const float bv[8] = {b0.x,b0.y,b0.z,b0.w,b1.x,b1.y,b1.z,b1.w};
      #pragma unroll
      for (int i=0;i<8;i++)
        #pragma unroll
        for (int j2=0;j2<8;j2++) acc[i][j2] = fmaf(av[i], bv[j2], acc[i][j2]);
    }
    __syncthreads();
  }
  #pragma unroll
  for (int i=0;i<8;i++){
    int gm = m0 + tm*8 + i;
    if (gm < Mrows){
      #pragma unroll
      for (int j2=0;j2<8;j2++){
        int gn = n0 + tn*8 + j2;
        if (gn < N){
          long long oi = (long long)gm*ldc + gn;
          float val = acc[i][j2] + bias[gn];
          if (MODE == 1) val = fmaxf(val, 0.f);
          if (MODE == 2) val += Co[oi];
          Co[oi] = val;
        }
      }
    }
  }
}

// ---------------------------------------------------------------------------
// Split-bf16 MFMA GEMM (f32-grade): Co[m,n] = sum_k A[m][k]*W[n][k] + bias[n]
// Requires: M % 128 == 0, N % 128 == 0, K % 32 == 0 (we only call with such).
// MODE 0: store; MODE 2: accumulate.
// ---------------------------------------------------------------------------
template<int MODE>
__global__ __launch_bounds__(256) void gemm_mf(
    const float* __restrict__ A, int lda,
    const float* __restrict__ W, int ldw,
    const float* __restrict__ bias,
    float* __restrict__ Co, int ldc,
    int N, int K)
{
  __shared__ __align__(16) unsigned short Ah[128*32];
  __shared__ __align__(16) unsigned short Al[128*32];
  __shared__ __align__(16) unsigned short Bh[128*32];
  __shared__ __align__(16) unsigned short Bl[128*32];
  const int t = threadIdx.x;
  const int m0 = blockIdx.x*128, n0 = blockIdx.y*128;
  const int lane = t & 63, w = t >> 6;
  const int wm = (w & 1)*64, wn = (w >> 1)*64;
  const int fr = lane & 15, fg = lane >> 4;

  f32x4 acc[4][4];
  #pragma unroll
  for (int i=0;i<4;i++)
    #pragma unroll
    for (int j=0;j<4;j++){ f32x4 z; z[0]=0;z[1]=0;z[2]=0;z[3]=0; acc[i][j]=z; }

  for (int k0=0; k0<K; k0+=32){
    #pragma unroll
    for (int cc=0; cc<2; cc++){
      const int c   = t + cc*256;
      const int row = c >> 2, kg = c & 3;
      const int byte = row*64 + ((kg*16) ^ (((row>>1)&3)<<4));
      {
        const float* ap = A + (size_t)(m0+row)*lda + k0 + kg*8;
        float v[8];
        *(float4*)&v[0] = *(const float4*)ap;
        *(float4*)&v[4] = *(const float4*)(ap+4);
        bf16x8 hi, lo; cvt8(v, hi, lo);
        *(bf16x8*)((char*)Ah + byte) = hi;
        *(bf16x8*)((char*)Al + byte) = lo;
      }
      {
        const float* bp = W + (size_t)(n0+row)*ldw + k0 + kg*8;
        float v[8];
        *(float4*)&v[0] = *(const float4*)bp;
        *(float4*)&v[4] = *(const float4*)(bp+4);
        bf16x8 hi, lo; cvt8(v, hi, lo);
        *(bf16x8*)((char*)Bh + byte) = hi;
        *(bf16x8*)((char*)Bl + byte) = lo;
      }
    }
    __syncthreads();
    bf16x8 ahi[4], alo[4], bhi[4], blo[4];
    #pragma unroll
    for (int mt=0; mt<4; mt++){
      const int r = wm + mt*16 + fr;
      const int byte = r*64 + ((fg*16) ^ (((r>>1)&3)<<4));
      ahi[mt] = *(const bf16x8*)((const char*)Ah + byte);
      alo[mt] = *(const bf16x8*)((const char*)Al + byte);
    }
    #pragma unroll
    for (int nt=0; nt<4; nt++){
      const int r = wn + nt*16 + fr;
      const int byte = r*64 + ((fg*16) ^ (((r>>1)&3)<<4));
      bhi[nt] = *(const bf16x8*)((const char*)Bh + byte);
      blo[nt] = *(const bf16x8*)((const char*)Bl + byte);
    }
    #pragma unroll
    for (int mt=0; mt<4; mt++)
      #pragma unroll
      for (int nt=0; nt<4; nt++){
        acc[mt][nt] = __builtin_amdgcn_mfma_f32_16x16x32_bf16(alo[mt], bhi[nt], acc[mt][nt], 0,0,0);
        acc[mt][nt] = __builtin_amdgcn_mfma_f32_16x16x32_bf16(ahi[mt], blo[nt], acc[mt][nt], 0,0,0);
        acc[mt][nt] = __builtin_amdgcn_mfma_f32_16x16x32_bf16(ahi[mt], bhi[nt], acc[mt][nt], 0,0,0);
      }
    __syncthreads();
  }

  #pragma unroll
  for (int mt=0; mt<4; mt++){
    #pragma unroll
    for (int nt=0; nt<4; nt++){
      const int col = n0 + wn + nt*16 + fr;
      const float bv = bias[col];
      #pragma unroll
      for (int i=0;i<4;i++){
        const int row = m0 + wm + mt*16 + fg*4 + i;
        const size_t oi = (size_t)row*ldc + col;
        float val = acc[mt][nt][i] + bv;
        if (MODE == 2) val += Co[oi];
        Co[oi] = val;
      }
    }
  }
}

// ---------------------------------------------------------------------------
// Dual-A fused out-projection GEMM: Co[m,n] = A1[m]·W[n,0:256] + A2[m]·W[n,256:512] + bias[n]
// ---------------------------------------------------------------------------
__global__ __launch_bounds__(256) void gemm_mf_dual(
    const float* __restrict__ A1, const float* __restrict__ A2,
    const float* __restrict__ W,
    const float* __restrict__ bias,
    float* __restrict__ Co, int ldc, int N)
{
  __shared__ __align__(16) unsigned short Ah[128*32];
  __shared__ __align__(16) unsigned short Al[128*32];
  __shared__ __align__(16) unsigned short Bh[128*32];
  __shared__ __align__(16) unsigned short Bl[128*32];
  const int t = threadIdx.x;
  const int m0 = blockIdx.x*128, n0 = blockIdx.y*128;
  const int lane = t & 63, w = t >> 6;
  const int wm = (w & 1)*64, wn = (w >> 1)*64;
  const int fr = lane & 15, fg = lane >> 4;

  f32x4 acc[4][4];
  #pragma unroll
  for (int i=0;i<4;i++)
    #pragma unroll
    for (int j=0;j<4;j++){ f32x4 z; z[0]=0;z[1]=0;z[2]=0;z[3]=0; acc[i][j]=z; }

  for (int k0=0; k0<2*HH; k0+=32){
    const float* Abase = (k0 < HH) ? A1 : A2;
    const int    kofs  = (k0 < HH) ? k0 : (k0 - HH);
    #pragma unroll
    for (int cc=0; cc<2; cc++){
      const int c   = t + cc*256;
      const int row = c >> 2, kg = c & 3;
      const int byte = row*64 + ((kg*16) ^ (((row>>1)&3)<<4));
      {
        const float* ap = Abase + (size_t)(m0+row)*HH + kofs + kg*8;
        float v[8];
        *(float4*)&v[0] = *(const float4*)ap;
        *(float4*)&v[4] = *(const float4*)(ap+4);
        bf16x8 hi, lo; cvt8(v, hi, lo);
        *(bf16x8*)((char*)Ah + byte) = hi;
        *(bf16x8*)((char*)Al + byte) = lo;
      }
      {
        const float* bp = W + (size_t)(n0+row)*(2*HH) + k0 + kg*8;
        float v[8];
        *(float4*)&v[0] = *(const float4*)bp;
        *(float4*)&v[4] = *(const float4*)(bp+4);
        bf16x8 hi, lo; cvt8(v, hi, lo);
        *(bf16x8*)((char*)Bh + byte) = hi;
        *(bf16x8*)((char*)Bl + byte) = lo;
      }
    }
    __syncthreads();
    bf16x8 ahi[4], alo[4], bhi[4], blo[4];
    #pragma unroll
    for (int mt=0; mt<4; mt++){
      const int r = wm + mt*16 + fr;
      const int byte = r*64 + ((fg*16) ^ (((r>>1)&3)<<4));
      ahi[mt] = *(const bf16x8*)((const char*)Ah + byte);
      alo[mt] = *(const bf16x8*)((const char*)Al + byte);
    }
    #pragma unroll
    for (int nt=0; nt<4; nt++){
      const int r = wn + nt*16 + fr;
      const int byte = r*64 + ((fg*16) ^ (((r>>1)&3)<<4));
      bhi[nt] = *(const bf16x8*)((const char*)Bh + byte);
      blo[nt] = *(const bf16x8*)((const char*)Bl + byte);
    }
    #pragma unroll
    for (int mt=0; mt<4; mt++)
      #pragma unroll
      for (int nt=0; nt<4; nt++){
        acc[mt][nt] = __builtin_amdgcn_mfma_f32_16x16x32_bf16(alo[mt], bhi[nt], acc[mt][nt], 0,0,0);
        acc[mt][nt] = __builtin_amdgcn_mfma_f32_16x16x32_bf16(ahi[mt], blo[nt], acc[mt][nt], 0,0,0);
        acc[mt][nt] = __builtin_amdgcn_mfma_f32_16x16x32_bf16(ahi[mt], bhi[nt], acc[mt][nt], 0,0,0);
      }
    __syncthreads();
  }

  #pragma unroll
  for (int mt=0; mt<4; mt++){
    #pragma unroll
    for (int nt=0; nt<4; nt++){
      const int col = n0 + wn + nt*16 + fr;
      const float bv = bias[col];
      #pragma unroll
      for (int i=0;i<4;i++){
        const int row = m0 + wm + mt*16 + fg*4 + i;
        const size_t oi = (size_t)row*ldc + col;
        Co[oi] = acc[mt][nt][i] + bv;
      }
    }
  }
}

// ---------------------------------------------------------------------------
// BatchNorm stats + fold
// ---------------------------------------------------------------------------
__global__ void bn_partial_k(const float* __restrict__ Xc, float* __restrict__ ps,
                             float* __restrict__ pq, int pblk0){
  int blk = blockIdx.x, t = threadIdx.x;
  long long base = (long long)blk*512*HH;
  float s = 0.f, q = 0.f;
  for (int r=0;r<512;r++){
    float v = Xc[base + (long long)r*HH + t];
    s += v; q = fmaf(v, v, q);
  }
  ps[(pblk0+blk)*HH + t] = s;
  pq[(pblk0+blk)*HH + t] = q;
}

__global__ void bn_final_k(const float* __restrict__ ps, const float* __restrict__ pq,
                           const float* __restrict__ g, const float* __restrict__ b,
                           float* __restrict__ sc, float* __restrict__ sh){
  int t = threadIdx.x;
  double s = 0.0, q = 0.0;
  for (int i=0;i<256;i++){ s += (double)ps[i*HH + t]; q += (double)pq[i*HH + t]; }
  double mu  = s / (double)SB;
  double var = q / (double)SB - mu*mu;
  float scv = (float)((double)g[t] / sqrt(var + 1e-5));
  sc[t] = scv;
  sh[t] = (float)((double)b[t] - mu*(double)scv);
}

__global__ void fold_k(const float* __restrict__ w, const float* __restrict__ b,
                       const float* __restrict__ sc, const float* __restrict__ sh,
                       float* __restrict__ wf, float* __restrict__ bf, int K){
  int idx = blockIdx.x*blockDim.x + threadIdx.x;
  if (idx < 256*K){ int o = idx / K; wf[idx] = w[idx]*sc[o]; }
  if (idx < 256)  bf[idx] = b[idx]*sc[idx] + sh[idx];
}

// ---------------------------------------------------------------------------
// LayerNorm over last dim (256), out-of-place. One block per row.
// ---------------------------------------------------------------------------
__global__ void ln_rows_k(const float* __restrict__ Xi, float* __restrict__ Xo,
                          const float* __restrict__ g, const float* __restrict__ b){
  long long row = blockIdx.x;
  int t = threadIdx.x;
  float v = Xi[row*HH + t];
  float s = v, q = v*v;
  #pragma unroll
  for (int o=32;o>0;o>>=1){ s += __shfl_down(s,o); q += __shfl_down(q,o); }
  __shared__ float ssm[4], qqm[4];
  int w = t >> 6;
  if ((t & 63) == 0){ ssm[w] = s; qqm[w] = q; }
  __syncthreads();
  if (t == 0){ ssm[0] = ssm[0]+ssm[1]+ssm[2]+ssm[3]; qqm[0] = qqm[0]+qqm[1]+qqm[2]+qqm[3]; }
  __syncthreads();
  s = ssm[0]; q = qqm[0];
  float mu  = s * (1.f/HH);
  float var = q * (1.f/HH) - mu*mu;
  float rs  = rsqrtf(var + EPSF);
  Xo[row*HH + t] = (v - mu)*rs*g[t] + b[t];
}

// ---------------------------------------------------------------------------
// k-split register-blocked GRU gate scan — proven 128x4 structure.
// L2 note: 16 concurrent scan blocks/XCD retain the 786KB whhT image in
// the 4MiB XCD L2 (FETCH 53MB/dispatch); 32/XCD thrashed (9.2GB). Keep 128.
// R3: inner k-loop unroll 4 -> 8. Diagnosis: 27% VALUBusy, ~100 GB/s/CU
// weight stream = latency-bound on L1-miss MLP (every line is an L1 miss,
// ~200cy L2-hit). Deeper unroll doubles outstanding float4 loads/thread
// (256B -> 512B in flight).
// ---------------------------------------------------------------------------
#define DOT4(hv,A0,A1,A2,A3) \
  A0=fmaf(hv.x,w0.x,A0); A0=fmaf(hv.y,w1.x,A0); A0=fmaf(hv.z,w2.x,A0); A0=fmaf(hv.w,w3.x,A0); \
  A1=fmaf(hv.x,w0.y,A1); A1=fmaf(hv.y,w1.y,A1); A1=fmaf(hv.z,w2.y,A1); A1=fmaf(hv.w,w3.y,A1); \
  A2=fmaf(hv.x,w0.z,A2); A2=fmaf(hv.y,w1.z,A2); A2=fmaf(hv.z,w2.z,A2); A2=fmaf(hv.w,w3.z,A2); \
  A3=fmaf(hv.x,w0.w,A3); A3=fmaf(hv.y,w1.w,A3); A3=fmaf(hv.z,w2.w,A3); A3=fmaf(hv.w,w3.w,A3);

__global__ __launch_bounds__(768) void gru_scan_ks_k(
  const float* __restrict__ gi,      // Rr x 768 (chunk-local)
  const float* __restrict__ whhT,    // 256 x 768 (k-major)
  const float* __restrict__ bhh,     // 768
  const float* __restrict__ mask0,   // mask + s0*BB
  float* __restrict__ hcar,          // B x 256 carry (in/out)
  float* __restrict__ Hh,            // Rr x 256 out: post-mask h per step
  int nst)
{
  const int t  = threadIdx.x;
  const int b0 = blockIdx.x*4;
  const int cg = t % 192;            // column group (4 cols)
  const int ks = t / 192;            // k-slice (64 k)
  const int c0 = cg*4;
  const int k0 = ks*64;
  __shared__ __align__(16) float h[4][260];
  __shared__ __align__(16) float part[4][4][776];
  __shared__ float mkz[4];

  const int uj = t & 255;            // update col (t < 512)
  const int ur = t >> 8;             // update rows ur, ur+2
  if (t < 512){
    h[ur  ][uj] = hcar[(size_t)(b0+ur  )*HH + uj];
    h[ur+2][uj] = hcar[(size_t)(b0+ur+2)*HH + uj];
  }
  float br=0.f, bz=0.f, bn_=0.f;
  if (t < 512){ br = bhh[uj]; bz = bhh[uj+HH]; bn_ = bhh[uj+2*HH]; }
  __syncthreads();

  const float* wbase = whhT + (size_t)k0*G3 + c0;

  for (int st=0; st<nst; ++st){
    float i0r=0,i0z=0,i0n=0, i1r=0,i1z=0,i1n=0;
    if (t < 512){
      const size_t ga = ((size_t)st*BB + b0 + ur  )*G3 + uj;
      const size_t gb = ((size_t)st*BB + b0 + ur+2)*G3 + uj;
      i0r=gi[ga]; i0z=gi[ga+HH]; i0n=gi[ga+2*HH];
      i1r=gi[gb]; i1z=gi[gb+HH]; i1n=gi[gb+2*HH];
    }
    if (t < 4) mkz[t] = mask0[(size_t)st*BB + b0 + t];

    float a00=0,a01=0,a02=0,a03=0;
    float a10=0,a11=0,a12=0,a13=0;
    float a20=0,a21=0,a22=0,a23=0;
    float a30=0,a31=0,a32=0,a33=0;
    #pragma unroll 8
    for (int kk=0; kk<64; kk+=4){
      const float4 w0 = *(const float4*)(wbase + (size_t)(kk  )*G3);
      const float4 w1 = *(const float4*)(wbase + (size_t)(kk+1)*G3);
      const float4 w2 = *(const float4*)(wbase + (size_t)(kk+2)*G3);
      const float4 w3 = *(const float4*)(wbase + (size_t)(kk+3)*G3);
      const float4 h0 = *(const float4*)&h[0][k0+kk];
      const float4 h1 = *(const float4*)&h[1][k0+kk];
      const float4 h2 = *(const float4*)&h[2][k0+kk];
      const float4 h3 = *(const float4*)&h[3][k0+kk];
      DOT4(h0,a00,a01,a02,a03);
      DOT4(h1,a10,a11,a12,a13);
      DOT4(h2,a20,a21,a22,a23);
      DOT4(h3,a30,a31,a32,a33);
    }
    *(float4*)&part[ks][0][c0] = make_float4(a00,a01,a02,a03);
    *(float4*)&part[ks][1][c0] = make_float4(a10,a11,a12,a13);
    *(float4*)&part[ks][2][c0] = make_float4(a20,a21,a22,a23);
    *(float4*)&part[ks][3][c0] = make_float4(a30,a31,a32,a33);
    __syncthreads();

    if (t < 512){
      {
        const int r_ = ur;
        const float ar = part[0][r_][uj]+part[1][r_][uj]+part[2][r_][uj]+part[3][r_][uj] + br;
        const float az = part[0][r_][uj+HH]+part[1][r_][uj+HH]+part[2][r_][uj+HH]+part[3][r_][uj+HH] + bz;
        const float an = part[0][r_][uj+2*HH]+part[1][r_][uj+2*HH]+part[2][r_][uj+2*HH]+part[3][r_][uj+2*HH] + bn_;
        const float rr = 1.f/(1.f + __expf(-(i0r + ar)));
        const float zz = 1.f/(1.f + __expf(-(i0z + az)));
        const float nn = tanhf(fmaf(rr, an, i0n));
        const float hold = h[r_][uj];
        const float m = mkz[r_];
        const float hnew = (1.f - zz)*nn + zz*hold;
        const float hv = hnew*m + hold*(1.f - m);
        h[r_][uj] = hv;
        Hh[((size_t)st*BB + b0 + r_)*HH + uj] = hv;
      }
      {
        const int r_ = ur + 2;
        const float ar = part[0][r_][uj]+part[1][r_][uj]+part[2][r_][uj]+part[3][r_][uj] + br;
        const float az = part[0][r_][uj+HH]+part[1][r_][uj+HH]+part[2][r_][uj+HH]+part[3][r_][uj+HH] + bz;
        const float an = part[0][r_][uj+2*HH]+part[1][r_][uj+2*HH]+part[2][r_][uj+2*HH]+part[3][r_][uj+2*HH] + bn_;
        const float rr = 1.f/(1.f + __expf(-(i1r + ar)));
        const float zz = 1.f/(1.f + __expf(-(i1z + az)));
        const float nn = tanhf(fmaf(rr, an, i1n));
        const float hold = h[r_][uj];
        const float m = mkz[r_];
        const float hnew = (1.f - zz)*nn + zz*hold;
        const float hv = hnew*m + hold*(1.f - m);
        h[r_][uj] = hv;
        Hh[((size_t)st*BB + b0 + r_)*HH + uj] = hv;
      }
    }
    __syncthreads();
  }
  if (t < 512){
    hcar[(size_t)(b0+ur  )*HH + uj] = h[ur  ][uj];
    hcar[(size_t)(b0+ur+2)*HH + uj] = h[ur+2][uj];
  }
}

// ---------------------------------------------------------------------------
// Head (fused LN2): x=LN2(row); relu(x@nn1.T+b1) -> LN(8) -> @nn2.T+b2.
// ---------------------------------------------------------------------------
__global__ void head_ln_k(const float* __restrict__ hx,
                          const float* __restrict__ g2, const float* __restrict__ b2,
                          const float* __restrict__ w1, const float* __restrict__ b1,
                          const float* __restrict__ g3, const float* __restrict__ b3,
                          const float* __restrict__ w2, const float* __restrict__ b2h,
                          float* __restrict__ outp, long long r0){
  long long row = blockIdx.x;
  int t = threadIdx.x;
  float v = hx[row*HH + t];
  float s = v, q = v*v;
  #pragma unroll
  for (int o=32;o>0;o>>=1){ s += __shfl_down(s,o); q += __shfl_down(q,o); }
  __shared__ float ssm[4], qqm[4];
  int w = t >> 6;
  if ((t & 63) == 0){ ssm[w] = s; qqm[w] = q; }
  __syncthreads();
  if (t == 0){ ssm[0] = ssm[0]+ssm[1]+ssm[2]+ssm[3]; qqm[0] = qqm[0]+qqm[1]+qqm[2]+qqm[3]; }
  __syncthreads();
  s = ssm[0]; q = qqm[0];
  float mu  = s * (1.f/HH);
  float var = q * (1.f/HH) - mu*mu;
  float rs  = rsqrtf(var + EPSF);
  __shared__ float xs[HH];
  xs[t] = (v - mu)*rs*g2[t] + b2[t];
  __syncthreads();
  int o = t >> 5, l = t & 31;
  const float* wv = w1 + o*HH;
  float acc = 0.f;
  for (int k=l;k<HH;k+=32) acc = fmaf(xs[k], wv[k], acc);
  #pragma unroll
  for (int d=16;d>0;d>>=1) acc += __shfl_down(acc, d, 32);
  __shared__ float a8[8];
  if (l == 0) a8[o] = fmaxf(acc + b1[o], 0.f);
  __syncthreads();
  if (t == 0){
    float ss = 0.f;
    #pragma unroll
    for (int i=0;i<8;i++) ss += a8[i];
    float m8 = ss*0.125f;
    float qq = 0.f;
    #pragma unroll
    for (int i=0;i<8;i++){ float d = a8[i]-m8; qq = fmaf(d,d,qq); }
    float r8 = rsqrtf(qq*0.125f + EPSF);
    float y0 = b2h[0], y1 = b2h[1];
    #pragma unroll
    for (int i=0;i<8;i++){
      float vv = (a8[i]-m8)*r8*g3[i] + b3[i];
      y0 = fmaf(vv, w2[i],   y0);
      y1 = fmaf(vv, w2[8+i], y1);
    }
    outp[(r0+row)*2+0] = y0; outp[(r0+row)*2+1] = y1;
  }
}

// ---------------------------------------------------------------------------
// Host launcher — adaptive S-chunked pipeline (unchanged from R2).
// ---------------------------------------------------------------------------
extern "C" void kernel_launch(void* const* d_in, const int* in_sizes, int n_in,
                              void* d_out, int out_size, void* d_ws, size_t ws_size,
                              hipStream_t stream) {
  const float* X      = (const float*)d_in[0];
  const float* Mi     = (const float*)d_in[1];
  const float* mask   = (const float*)d_in[2];
  const float* i2h_w  = (const float*)d_in[3];
  const float* i2h_b  = (const float*)d_in[4];
  const float* comb_w = (const float*)d_in[5];
  const float* comb_b = (const float*)d_in[6];
  const float* down_w = (const float*)d_in[7];
  const float* down_b = (const float*)d_in[8];
  const float* conv1_w= (const float*)d_in[9];
  const float* conv1_b= (const float*)d_in[10];
  const float* conv2_w= (const float*)d_in[11];
  const float* conv2_b= (const float*)d_in[12];
  const float* bn1_g  = (const float*)d_in[13];
  const float* bn1_b  = (const float*)d_in[14];
  const float* bn2_g  = (const float*)d_in[15];
  const float* bn2_b  = (const float*)d_in[16];
  const float* r1_wih = (const float*)d_in[17];
  const float* r1_whh = (const float*)d_in[18];
  const float* r1_bih = (const float*)d_in[19];
  const float* r1_bhh = (const float*)d_in[20];
  const float* r1_cw  = (const float*)d_in[21];
  const float* r1_cb  = (const float*)d_in[22];
  const float* r2_wih = (const float*)d_in[23];
  const float* r2_whh = (const float*)d_in[24];
  const float* r2_bih = (const float*)d_in[25];
  const float* r2_bhh = (const float*)d_in[26];
  const float* r2_cw  = (const float*)d_in[27];
  const float* r2_cb  = (const float*)d_in[28];
  const float* ln1_g  = (const float*)d_in[29];
  const float* ln1_b  = (const float*)d_in[30];
  const float* ln2_g  = (const float*)d_in[31];
  const float* ln2_b  = (const float*)d_in[32];
  const float* ln3_g  = (const float*)d_in[33];
  const float* ln3_b  = (const float*)d_in[34];
  const float* nn1_w  = (const float*)d_in[35];
  const float* nn1_b  = (const float*)d_in[36];
  const float* nn2_w  = (const float*)d_in[37];
  const float* nn2_b  = (const float*)d_in[38];
  float* outp = (float*)d_out;

  // tail: H1C,H2C | PS,PQ | SCv,SHv | W1F,B1F | W2F,B2F | W1T,W2T | XcF
  const size_t tail_floats = 2*(size_t)BB*HH + 2*(size_t)256*HH + 2*HH
                           + (size_t)256*40 + 256 + (size_t)HH*HH + 256
                           + 2*(size_t)G3*HH + (size_t)SB*CC;
  // per-chunk: A + GIc + Cxp + Ee = 256+768+256+256 = 1536 floats/row
  int cands[6] = {256,128,64,32,16,8};
  int sc_chunk = 0;
  for (int ci=0; ci<6; ci++){
    size_t R = (size_t)512*cands[ci];
    size_t need = (R*1536 + tail_floats)*sizeof(float);
    if (need <= ws_size){ sc_chunk = cands[ci]; break; }
  }
  if (!sc_chunk) return;

  const size_t R = (size_t)512*sc_chunk;     // rows per chunk
  const int Ri = (int)R;
  const int nchunks = SB / Ri;

  float* wsf = (float*)d_ws;
  float* A   = wsf;                    // R*256
  float* GIc = A + R*HH;               // R*768
  float* Cxp = GIc + R*G3;             // R*256
  float* Ee  = Cxp + R*HH;             // R*256
  float* tl  = Ee + R*HH;
  float* H1C = tl;                     // BB*HH
  float* H2C = H1C + (size_t)BB*HH;
  float* PS  = H2C + (size_t)BB*HH;    // 256*HH
  float* PQ  = PS  + (size_t)256*HH;
  float* SCv = PQ  + (size_t)256*HH;   // HH
  float* SHv = SCv + HH;
  float* W1F = SHv + HH;               // 256*40
  float* B1F = W1F + (size_t)256*40;   // 256
  float* W2F = B1F + HH;               // 256*256
  float* B2F = W2F + (size_t)HH*HH;    // 256
  float* W1T = B2F + HH;               // 256*768 whhT (GRU1)
  float* W2T = W1T + (size_t)HH*G3;    // 256*768 whhT (GRU2)
  float* XcF = W2T + (size_t)HH*G3;    // SB*40 persisted comb output

  // one-time weight transposes for the scans
  whht_k<<<(G3*HH + 255)/256, 256, 0, stream>>>(r1_whh, W1T);
  whht_k<<<(G3*HH + 255)/256, 256, 0, stream>>>(r2_whh, W2T);

  const int PACKG = (Ri*80 + 255)/256;
  const int MB = Ri/128;

  // ---------- pass A: pack+comb once (persist Xc), BN1 stats ----------
  for (int c=0;c<nchunks;c++){
    long long r0 = (long long)c*R;
    pack_xm_chunk_k<<<PACKG, 256, 0, stream>>>(X, Mi, Ee, r0, Ri);
    gemm_tn<0><<<dim3(MB,1), 256, 0, stream>>>(Ee, 80, comb_w, 80, comb_b, XcF + r0*CC, CC, Ri, CC, 80);
    gemm_tn<0><<<dim3(MB,2), 256, 0, stream>>>(XcF + r0*CC, CC, conv1_w, CC, conv1_b, Ee, HH, Ri, HH, CC);
    bn_partial_k<<<Ri/512, 256, 0, stream>>>(Ee, PS, PQ, (int)(r0/512));
  }
  bn_final_k<<<1, 256, 0, stream>>>(PS, PQ, bn1_g, bn1_b, SCv, SHv);
  fold_k<<<(256*40 + 255)/256, 256, 0, stream>>>(conv1_w, conv1_b, SCv, SHv, W1F, B1F, 40);

  // ---------- pass B: BN2 stats (conv2 raw on folded-relu out1) ----------
  for (int c=0;c<nchunks;c++){
    long long r0 = (long long)c*R;
    gemm_tn<1><<<dim3(MB,2), 256, 0, stream>>>(XcF + r0*CC, CC, W1F, CC, B1F, Ee, HH, Ri, HH, CC);
    gemm_mf<0><<<dim3(MB,2), 256, 0, stream>>>(Ee, HH, conv2_w, HH, conv2_b, A, HH, HH, HH);
    bn_partial_k<<<Ri/512, 256, 0, stream>>>(A, PS, PQ, (int)(r0/512));
  }
  bn_final_k<<<1, 256, 0, stream>>>(PS, PQ, bn2_g, bn2_b, SCv, SHv);
  fold_k<<<(256*256 + 255)/256, 256, 0, stream>>>(conv2_w, conv2_b, SCv, SHv, W2F, B2F, 256);

  // ---------- h0 -> carries ----------
  h0_k<<<BB, HH, 0, stream>>>(X, i2h_w, i2h_b, H1C, H2C);

  // ---------- pass C: main pipeline ----------
  for (int c=0;c<nchunks;c++){
    long long r0 = (long long)c*R;
    // res = Xin @ down_w^T  (read X directly, lda=II, first 40 cols)
    gemm_tn<0><<<dim3(MB,2), 256, 0, stream>>>(X + r0*II, II, down_w, CC, down_b, A, HH, Ri, HH, CC);
    // out1r = relu(bn1-folded conv1(Xc))
    gemm_tn<1><<<dim3(MB,2), 256, 0, stream>>>(XcF + r0*CC, CC, W1F, CC, B1F, Ee, HH, Ri, HH, CC);
    // hx = bn2-folded conv2(out1r) + res
    gemm_mf<2><<<dim3(MB,2), 256, 0, stream>>>(Ee, HH, W2F, HH, B2F, A, HH, HH, HH);
    // GRU1
    gemm_mf<0><<<dim3(MB,6), 256, 0, stream>>>(A, HH, r1_wih, HH, r1_bih, GIc, G3, G3, HH);
    gru_scan_ks_k<<<BB/4, 768, 0, stream>>>(GIc, W1T, r1_bhh, mask + r0, H1C, Ee, sc_chunk);   // Hh1 -> Ee
    gemm_mf_dual<<<dim3(MB,2), 256, 0, stream>>>(A, Ee, r1_cw, r1_cb, Cxp, HH, HH);            // outs1 = [hx|Hh1]@cw^T
    ln_rows_k<<<Ri, 256, 0, stream>>>(Cxp, Ee, ln1_g, ln1_b);                                   // hx1 -> Ee
    // GRU2
    gemm_mf<0><<<dim3(MB,6), 256, 0, stream>>>(Ee, HH, r2_wih, HH, r2_bih, GIc, G3, G3, HH);
    gru_scan_ks_k<<<BB/4, 768, 0, stream>>>(GIc, W2T, r2_bhh, mask + r0, H2C, A, sc_chunk);    // Hh2 -> A
    gemm_mf_dual<<<dim3(MB,2), 256, 0, stream>>>(Ee, A, r2_cw, r2_cb, Cxp, HH, HH);            // outs2 = [hx1|Hh2]@cw^T
    // head (LN2 fused)
    head_ln_k<<<Ri, 256, 0, stream>>>(Cxp, ln2_g, ln2_b, nn1_w, nn1_b, ln3_g, ln3_b, nn2_w, nn2_b, outp, r0);
  }
}

// Round 4
// 6609.454 us; speedup vs baseline: 1.0684x; 1.0684x over previous
//
#include <hip/hip_runtime.h>
#include <hip/hip_bf16.h>

// Problem dims
#define SS 256
#define BB 512
#define II 46
#define HH 256
#define CC 40
#define SB (SS*BB)        // 131072 rows
#define G3 (3*HH)         // 768
#define EPSF 1e-5f

typedef __attribute__((ext_vector_type(8))) short bf16x8;
typedef __attribute__((ext_vector_type(4))) float f32x4;

// ---------------------------------------------------------------------------
// helpers
// ---------------------------------------------------------------------------
__device__ __forceinline__ unsigned short f2bf_rne(float f){
  unsigned u = __float_as_uint(f);
  unsigned r = (u + 0x7FFFu + ((u >> 16) & 1u)) >> 16;
  return (unsigned short)r;
}
__device__ __forceinline__ float bf2f(unsigned short b){
  return __uint_as_float(((unsigned)b) << 16);
}
__device__ __forceinline__ void cvt8(const float* v, bf16x8& hi, bf16x8& lo){
  #pragma unroll
  for (int e=0;e<8;e++){
    unsigned short hb = f2bf_rne(v[e]);
    hi[e] = (short)hb;
    lo[e] = (short)f2bf_rne(v[e] - bf2f(hb));
  }
}

// ---------------------------------------------------------------------------
// pack XM chunk = [Xin | Min]  (Rr x 80) from X,M rows [r0, r0+Rr)
// (pass A only now — Xc persisted afterwards)
// ---------------------------------------------------------------------------
__global__ void pack_xm_chunk_k(const float* __restrict__ X, const float* __restrict__ Mi,
                                float* __restrict__ XM, long long r0, int Rr){
  long long idx = (long long)blockIdx.x*blockDim.x + threadIdx.x;
  if (idx >= (long long)Rr*80) return;
  int r = (int)(idx / 80);
  int c = (int)(idx - (long long)r*80);
  long long gr = r0 + r;
  float v;
  if (c < CC) v = X[gr*II + c];
  else        v = Mi[gr*II + (c - CC)];
  XM[idx] = v;
}

// ---------------------------------------------------------------------------
// h0[b,j] = sum_{c<6} X[0,b,40+c] * i2h_w[j,c] + i2h_b[j]  -> both carries
// ---------------------------------------------------------------------------
__global__ void h0_k(const float* __restrict__ X, const float* __restrict__ w,
                     const float* __restrict__ bias, float* __restrict__ h1c,
                     float* __restrict__ h2c){
  int b = blockIdx.x, jj = threadIdx.x;
  const float* p = X + (long long)b*II + (II - 6);
  float acc = bias[jj];
  #pragma unroll
  for (int c2=0;c2<6;c2++) acc = fmaf(p[c2], w[jj*6 + c2], acc);
  h1c[(long long)b*HH + jj] = acc;
  h2c[(long long)b*HH + jj] = acc;
}

// ---------------------------------------------------------------------------
// transpose whh (768x256) -> whhT (256x768), once per launch
// ---------------------------------------------------------------------------
__global__ void whht_k(const float* __restrict__ w, float* __restrict__ wt){
  int idx = blockIdx.x*blockDim.x + threadIdx.x;
  if (idx >= G3*HH) return;
  int u = idx / HH, k = idx - u*HH;      // w[u][k]
  wt[(size_t)k*G3 + u] = w[idx];
}

// ---------------------------------------------------------------------------
// Generic f32 GEMM (small-K ops only: comb K=80, down/conv1 K=40).
// MODE 0: store; MODE 1: store relu; MODE 2: accumulate
// ---------------------------------------------------------------------------
template<int MODE>
__global__ void gemm_tn(const float* __restrict__ A, int lda,
                        const float* __restrict__ W, int ldw,
                        const float* __restrict__ bias,
                        float* __restrict__ Co, int ldc,
                        int Mrows, int N, int K)
{
  __shared__ __align__(16) float As[32][132];
  __shared__ __align__(16) float Ws[32][132];
  const int m0 = blockIdx.x*128, n0 = blockIdx.y*128;
  const int t  = threadIdx.x;
  const int tm = t >> 4, tn = t & 15;
  float acc[8][8];
  #pragma unroll
  for (int i=0;i<8;i++)
    #pragma unroll
    for (int j2=0;j2<8;j2++) acc[i][j2] = 0.f;

  for (int k0=0;k0<K;k0+=32){
    #pragma unroll
    for (int u=0;u<16;u++){
      int idx = u*256 + t;
      int r = idx >> 5, c = idx & 31;
      int gk = k0 + c;
      float av = 0.f, wv = 0.f;
      if (gk < K){
        int gm = m0 + r;
        if (gm < Mrows) av = A[(long long)gm*lda + gk];
        int gn = n0 + r;
        if (gn < N)     wv = W[(long long)gn*ldw + gk];
      }
      As[c][r] = av;
      Ws[c][r] = wv;
    }
    __syncthreads();
    #pragma unroll
    for (int kk=0;kk<32;kk++){
      const float4 a0 = *(const float4*)&As[kk][tm*8];
      const float4 a1 = *(const float4*)&As[kk][tm*8+4];
      const float4 b0 = *(const float4*)&Ws[kk][tn*8];
      const float4 b1 = *(const float4*)&Ws[kk][tn*8+4];
      const float av[8] = {a0.x,a0.y,a0.z,a0.w,a1.x,a1.y,a1.z,a1.w};
      const float bv[8] = {b0.x,b0.y,b0.z,b0.w,b1.x,b1.y,b1.z,b1.w};
      #pragma unroll
      for (int i=0;i<8;i++)
        #pragma unroll
        for (int j2=0;j2<8;j2++) acc[i][j2] = fmaf(av[i], bv[j2], acc[i][j2]);
    }
    __syncthreads();
  }
  #pragma unroll
  for (int i=0;i<8;i++){
    int gm = m0 + tm*8 + i;
    if (gm < Mrows){
      #pragma unroll
      for (int j2=0;j2<8;j2++){
        int gn = n0 + tn*8 + j2;
        if (gn < N){
          long long oi = (long long)gm*ldc + gn;
          float val = acc[i][j2] + bias[gn];
          if (MODE == 1) val = fmaxf(val, 0.f);
          if (MODE == 2) val += Co[oi];
          Co[oi] = val;
        }
      }
    }
  }
}

// ---------------------------------------------------------------------------
// Split-bf16 MFMA GEMM (f32-grade): Co[m,n] = sum_k A[m][k]*W[n][k] + bias[n]
// Requires: M % 128 == 0, N % 128 == 0, K % 32 == 0 (we only call with such).
// MODE 0: store; MODE 2: accumulate.
// ---------------------------------------------------------------------------
template<int MODE>
__global__ __launch_bounds__(256) void gemm_mf(
    const float* __restrict__ A, int lda,
    const float* __restrict__ W, int ldw,
    const float* __restrict__ bias,
    float* __restrict__ Co, int ldc,
    int N, int K)
{
  __shared__ __align__(16) unsigned short Ah[128*32];
  __shared__ __align__(16) unsigned short Al[128*32];
  __shared__ __align__(16) unsigned short Bh[128*32];
  __shared__ __align__(16) unsigned short Bl[128*32];
  const int t = threadIdx.x;
  const int m0 = blockIdx.x*128, n0 = blockIdx.y*128;
  const int lane = t & 63, w = t >> 6;
  const int wm = (w & 1)*64, wn = (w >> 1)*64;
  const int fr = lane & 15, fg = lane >> 4;

  f32x4 acc[4][4];
  #pragma unroll
  for (int i=0;i<4;i++)
    #pragma unroll
    for (int j=0;j<4;j++){ f32x4 z; z[0]=0;z[1]=0;z[2]=0;z[3]=0; acc[i][j]=z; }

  for (int k0=0; k0<K; k0+=32){
    #pragma unroll
    for (int cc=0; cc<2; cc++){
      const int c   = t + cc*256;
      const int row = c >> 2, kg = c & 3;
      const int byte = row*64 + ((kg*16) ^ (((row>>1)&3)<<4));
      {
        const float* ap = A + (size_t)(m0+row)*lda + k0 + kg*8;
        float v[8];
        *(float4*)&v[0] = *(const float4*)ap;
        *(float4*)&v[4] = *(const float4*)(ap+4);
        bf16x8 hi, lo; cvt8(v, hi, lo);
        *(bf16x8*)((char*)Ah + byte) = hi;
        *(bf16x8*)((char*)Al + byte) = lo;
      }
      {
        const float* bp = W + (size_t)(n0+row)*ldw + k0 + kg*8;
        float v[8];
        *(float4*)&v[0] = *(const float4*)bp;
        *(float4*)&v[4] = *(const float4*)(bp+4);
        bf16x8 hi, lo; cvt8(v, hi, lo);
        *(bf16x8*)((char*)Bh + byte) = hi;
        *(bf16x8*)((char*)Bl + byte) = lo;
      }
    }
    __syncthreads();
    bf16x8 ahi[4], alo[4], bhi[4], blo[4];
    #pragma unroll
    for (int mt=0; mt<4; mt++){
      const int r = wm + mt*16 + fr;
      const int byte = r*64 + ((fg*16) ^ (((r>>1)&3)<<4));
      ahi[mt] = *(const bf16x8*)((const char*)Ah + byte);
      alo[mt] = *(const bf16x8*)((const char*)Al + byte);
    }
    #pragma unroll
    for (int nt=0; nt<4; nt++){
      const int r = wn + nt*16 + fr;
      const int byte = r*64 + ((fg*16) ^ (((r>>1)&3)<<4));
      bhi[nt] = *(const bf16x8*)((const char*)Bh + byte);
      blo[nt] = *(const bf16x8*)((const char*)Bl + byte);
    }
    #pragma unroll
    for (int mt=0; mt<4; mt++)
      #pragma unroll
      for (int nt=0; nt<4; nt++){
        acc[mt][nt] = __builtin_amdgcn_mfma_f32_16x16x32_bf16(alo[mt], bhi[nt], acc[mt][nt], 0,0,0);
        acc[mt][nt] = __builtin_amdgcn_mfma_f32_16x16x32_bf16(ahi[mt], blo[nt], acc[mt][nt], 0,0,0);
        acc[mt][nt] = __builtin_amdgcn_mfma_f32_16x16x32_bf16(ahi[mt], bhi[nt], acc[mt][nt], 0,0,0);
      }
    __syncthreads();
  }

  #pragma unroll
  for (int mt=0; mt<4; mt++){
    #pragma unroll
    for (int nt=0; nt<4; nt++){
      const int col = n0 + wn + nt*16 + fr;
      const float bv = bias[col];
      #pragma unroll
      for (int i=0;i<4;i++){
        const int row = m0 + wm + mt*16 + fg*4 + i;
        const size_t oi = (size_t)row*ldc + col;
        float val = acc[mt][nt][i] + bv;
        if (MODE == 2) val += Co[oi];
        Co[oi] = val;
      }
    }
  }
}

// ---------------------------------------------------------------------------
// Dual-A fused out-projection GEMM: Co[m,n] = A1[m]·W[n,0:256] + A2[m]·W[n,256:512] + bias[n]
// ---------------------------------------------------------------------------
__global__ __launch_bounds__(256) void gemm_mf_dual(
    const float* __restrict__ A1, const float* __restrict__ A2,
    const float* __restrict__ W,
    const float* __restrict__ bias,
    float* __restrict__ Co, int ldc, int N)
{
  __shared__ __align__(16) unsigned short Ah[128*32];
  __shared__ __align__(16) unsigned short Al[128*32];
  __shared__ __align__(16) unsigned short Bh[128*32];
  __shared__ __align__(16) unsigned short Bl[128*32];
  const int t = threadIdx.x;
  const int m0 = blockIdx.x*128, n0 = blockIdx.y*128;
  const int lane = t & 63, w = t >> 6;
  const int wm = (w & 1)*64, wn = (w >> 1)*64;
  const int fr = lane & 15, fg = lane >> 4;

  f32x4 acc[4][4];
  #pragma unroll
  for (int i=0;i<4;i++)
    #pragma unroll
    for (int j=0;j<4;j++){ f32x4 z; z[0]=0;z[1]=0;z[2]=0;z[3]=0; acc[i][j]=z; }

  for (int k0=0; k0<2*HH; k0+=32){
    const float* Abase = (k0 < HH) ? A1 : A2;
    const int    kofs  = (k0 < HH) ? k0 : (k0 - HH);
    #pragma unroll
    for (int cc=0; cc<2; cc++){
      const int c   = t + cc*256;
      const int row = c >> 2, kg = c & 3;
      const int byte = row*64 + ((kg*16) ^ (((row>>1)&3)<<4));
      {
        const float* ap = Abase + (size_t)(m0+row)*HH + kofs + kg*8;
        float v[8];
        *(float4*)&v[0] = *(const float4*)ap;
        *(float4*)&v[4] = *(const float4*)(ap+4);
        bf16x8 hi, lo; cvt8(v, hi, lo);
        *(bf16x8*)((char*)Ah + byte) = hi;
        *(bf16x8*)((char*)Al + byte) = lo;
      }
      {
        const float* bp = W + (size_t)(n0+row)*(2*HH) + k0 + kg*8;
        float v[8];
        *(float4*)&v[0] = *(const float4*)bp;
        *(float4*)&v[4] = *(const float4*)(bp+4);
        bf16x8 hi, lo; cvt8(v, hi, lo);
        *(bf16x8*)((char*)Bh + byte) = hi;
        *(bf16x8*)((char*)Bl + byte) = lo;
      }
    }
    __syncthreads();
    bf16x8 ahi[4], alo[4], bhi[4], blo[4];
    #pragma unroll
    for (int mt=0; mt<4; mt++){
      const int r = wm + mt*16 + fr;
      const int byte = r*64 + ((fg*16) ^ (((r>>1)&3)<<4));
      ahi[mt] = *(const bf16x8*)((const char*)Ah + byte);
      alo[mt] = *(const bf16x8*)((const char*)Al + byte);
    }
    #pragma unroll
    for (int nt=0; nt<4; nt++){
      const int r = wn + nt*16 + fr;
      const int byte = r*64 + ((fg*16) ^ (((r>>1)&3)<<4));
      bhi[nt] = *(const bf16x8*)((const char*)Bh + byte);
      blo[nt] = *(const bf16x8*)((const char*)Bl + byte);
    }
    #pragma unroll
    for (int mt=0; mt<4; mt++)
      #pragma unroll
      for (int nt=0; nt<4; nt++){
        acc[mt][nt] = __builtin_amdgcn_mfma_f32_16x16x32_bf16(alo[mt], bhi[nt], acc[mt][nt], 0,0,0);
        acc[mt][nt] = __builtin_amdgcn_mfma_f32_16x16x32_bf16(ahi[mt], blo[nt], acc[mt][nt], 0,0,0);
        acc[mt][nt] = __builtin_amdgcn_mfma_f32_16x16x32_bf16(ahi[mt], bhi[nt], acc[mt][nt], 0,0,0);
      }
    __syncthreads();
  }

  #pragma unroll
  for (int mt=0; mt<4; mt++){
    #pragma unroll
    for (int nt=0; nt<4; nt++){
      const int col = n0 + wn + nt*16 + fr;
      const float bv = bias[col];
      #pragma unroll
      for (int i=0;i<4;i++){
        const int row = m0 + wm + mt*16 + fg*4 + i;
        const size_t oi = (size_t)row*ldc + col;
        Co[oi] = acc[mt][nt][i] + bv;
      }
    }
  }
}

// ---------------------------------------------------------------------------
// BatchNorm stats + fold
// ---------------------------------------------------------------------------
__global__ void bn_partial_k(const float* __restrict__ Xc, float* __restrict__ ps,
                             float* __restrict__ pq, int pblk0){
  int blk = blockIdx.x, t = threadIdx.x;
  long long base = (long long)blk*512*HH;
  float s = 0.f, q = 0.f;
  for (int r=0;r<512;r++){
    float v = Xc[base + (long long)r*HH + t];
    s += v; q = fmaf(v, v, q);
  }
  ps[(pblk0+blk)*HH + t] = s;
  pq[(pblk0+blk)*HH + t] = q;
}

__global__ void bn_final_k(const float* __restrict__ ps, const float* __restrict__ pq,
                           const float* __restrict__ g, const float* __restrict__ b,
                           float* __restrict__ sc, float* __restrict__ sh){
  int t = threadIdx.x;
  double s = 0.0, q = 0.0;
  for (int i=0;i<256;i++){ s += (double)ps[i*HH + t]; q += (double)pq[i*HH + t]; }
  double mu  = s / (double)SB;
  double var = q / (double)SB - mu*mu;
  float scv = (float)((double)g[t] / sqrt(var + 1e-5));
  sc[t] = scv;
  sh[t] = (float)((double)b[t] - mu*(double)scv);
}

__global__ void fold_k(const float* __restrict__ w, const float* __restrict__ b,
                       const float* __restrict__ sc, const float* __restrict__ sh,
                       float* __restrict__ wf, float* __restrict__ bf, int K){
  int idx = blockIdx.x*blockDim.x + threadIdx.x;
  if (idx < 256*K){ int o = idx / K; wf[idx] = w[idx]*sc[o]; }
  if (idx < 256)  bf[idx] = b[idx]*sc[idx] + sh[idx];
}

// ---------------------------------------------------------------------------
// LayerNorm over last dim (256), out-of-place. One block per row.
// ---------------------------------------------------------------------------
__global__ void ln_rows_k(const float* __restrict__ Xi, float* __restrict__ Xo,
                          const float* __restrict__ g, const float* __restrict__ b){
  long long row = blockIdx.x;
  int t = threadIdx.x;
  float v = Xi[row*HH + t];
  float s = v, q = v*v;
  #pragma unroll
  for (int o=32;o>0;o>>=1){ s += __shfl_down(s,o); q += __shfl_down(q,o); }
  __shared__ float ssm[4], qqm[4];
  int w = t >> 6;
  if ((t & 63) == 0){ ssm[w] = s; qqm[w] = q; }
  __syncthreads();
  if (t == 0){ ssm[0] = ssm[0]+ssm[1]+ssm[2]+ssm[3]; qqm[0] = qqm[0]+qqm[1]+qqm[2]+qqm[3]; }
  __syncthreads();
  s = ssm[0]; q = qqm[0];
  float mu  = s * (1.f/HH);
  float var = q * (1.f/HH) - mu*mu;
  float rs  = rsqrtf(var + EPSF);
  Xo[row*HH + t] = (v - mu)*rs*g[t] + b[t];
}

// ---------------------------------------------------------------------------
// k-split register-blocked GRU gate scan — proven 128x4 structure, unroll 4
// (R3's unroll-8 regressed 498->555us: compiler didn't deepen the pipeline,
// just worsened the schedule — per-thread MLP is NOT the limiter).
// L2 note: 16 scan blocks/XCD retain the 786KB whhT in the 4MiB XCD L2
// (FETCH = gi stream only); 32/XCD thrashed (9.2GB). Keep 128 blocks.
// R4: per-block COLUMN ROTATION. All blocks used to sweep whhT in the same
// order in lockstep -> 16 CUs/XCD hit the same L2 lines simultaneously ->
// bank-serialized delivery (~50 GB/s/CU observed vs 134 ubench). Rotating
// each block's column start (23 coprime w/ 192; 16 distinct offsets per
// XCD for blockIdx stepping by 8) spreads concurrent requests across L2.
// part[] is indexed by the actual column, so the gate phase is unchanged.
// ---------------------------------------------------------------------------
#define DOT4(hv,A0,A1,A2,A3) \
  A0=fmaf(hv.x,w0.x,A0); A0=fmaf(hv.y,w1.x,A0); A0=fmaf(hv.z,w2.x,A0); A0=fmaf(hv.w,w3.x,A0); \
  A1=fmaf(hv.x,w0.y,A1); A1=fmaf(hv.y,w1.y,A1); A1=fmaf(hv.z,w2.y,A1); A1=fmaf(hv.w,w3.y,A1); \
  A2=fmaf(hv.x,w0.z,A2); A2=fmaf(hv.y,w1.z,A2); A2=fmaf(hv.z,w2.z,A2); A2=fmaf(hv.w,w3.z,A2); \
  A3=fmaf(hv.x,w0.w,A3); A3=fmaf(hv.y,w1.w,A3); A3=fmaf(hv.z,w2.w,A3); A3=fmaf(hv.w,w3.w,A3);

__global__ __launch_bounds__(768) void gru_scan_ks_k(
  const float* __restrict__ gi,      // Rr x 768 (chunk-local)
  const float* __restrict__ whhT,    // 256 x 768 (k-major)
  const float* __restrict__ bhh,     // 768
  const float* __restrict__ mask0,   // mask + s0*BB
  float* __restrict__ hcar,          // B x 256 carry (in/out)
  float* __restrict__ Hh,            // Rr x 256 out: post-mask h per step
  int nst)
{
  const int t  = threadIdx.x;
  const int b0 = blockIdx.x*4;
  const int cg = t % 192;            // column group (4 cols)
  const int ks = t / 192;            // k-slice (64 k)
  const int rot = (blockIdx.x * 23) % 192;
  const int c0 = ((cg + rot) % 192) * 4;   // rotated column start (bijective)
  const int k0 = ks*64;
  __shared__ __align__(16) float h[4][260];
  __shared__ __align__(16) float part[4][4][776];
  __shared__ float mkz[4];

  const int uj = t & 255;            // update col (t < 512)
  const int ur = t >> 8;             // update rows ur, ur+2
  if (t < 512){
    h[ur  ][uj] = hcar[(size_t)(b0+ur  )*HH + uj];
    h[ur+2][uj] = hcar[(size_t)(b0+ur+2)*HH + uj];
  }
  float br=0.f, bz=0.f, bn_=0.f;
  if (t < 512){ br = bhh[uj]; bz = bhh[uj+HH]; bn_ = bhh[uj+2*HH]; }
  __syncthreads();

  const float* wbase = whhT + (size_t)k0*G3 + c0;

  for (int st=0; st<nst; ++st){
    float i0r=0,i0z=0,i0n=0, i1r=0,i1z=0,i1n=0;
    if (t < 512){
      const size_t ga = ((size_t)st*BB + b0 + ur  )*G3 + uj;
      const size_t gb = ((size_t)st*BB + b0 + ur+2)*G3 + uj;
      i0r=gi[ga]; i0z=gi[ga+HH]; i0n=gi[ga+2*HH];
      i1r=gi[gb]; i1z=gi[gb+HH]; i1n=gi[gb+2*HH];
    }
    if (t < 4) mkz[t] = mask0[(size_t)st*BB + b0 + t];

    float a00=0,a01=0,a02=0,a03=0;
    float a10=0,a11=0,a12=0,a13=0;
    float a20=0,a21=0,a22=0,a23=0;
    float a30=0,a31=0,a32=0,a33=0;
    #pragma unroll 4
    for (int kk=0; kk<64; kk+=4){
      const float4 w0 = *(const float4*)(wbase + (size_t)(kk  )*G3);
      const float4 w1 = *(const float4*)(wbase + (size_t)(kk+1)*G3);
      const float4 w2 = *(const float4*)(wbase + (size_t)(kk+2)*G3);
      const float4 w3 = *(const float4*)(wbase + (size_t)(kk+3)*G3);
      const float4 h0 = *(const float4*)&h[0][k0+kk];
      const float4 h1 = *(const float4*)&h[1][k0+kk];
      const float4 h2 = *(const float4*)&h[2][k0+kk];
      const float4 h3 = *(const float4*)&h[3][k0+kk];
      DOT4(h0,a00,a01,a02,a03);
      DOT4(h1,a10,a11,a12,a13);
      DOT4(h2,a20,a21,a22,a23);
      DOT4(h3,a30,a31,a32,a33);
    }
    *(float4*)&part[ks][0][c0] = make_float4(a00,a01,a02,a03);
    *(float4*)&part[ks][1][c0] = make_float4(a10,a11,a12,a13);
    *(float4*)&part[ks][2][c0] = make_float4(a20,a21,a22,a23);
    *(float4*)&part[ks][3][c0] = make_float4(a30,a31,a32,a33);
    __syncthreads();

    if (t < 512){
      {
        const int r_ = ur;
        const float ar = part[0][r_][uj]+part[1][r_][uj]+part[2][r_][uj]+part[3][r_][uj] + br;
        const float az = part[0][r_][uj+HH]+part[1][r_][uj+HH]+part[2][r_][uj+HH]+part[3][r_][uj+HH] + bz;
        const float an = part[0][r_][uj+2*HH]+part[1][r_][uj+2*HH]+part[2][r_][uj+2*HH]+part[3][r_][uj+2*HH] + bn_;
        const float rr = 1.f/(1.f + __expf(-(i0r + ar)));
        const float zz = 1.f/(1.f + __expf(-(i0z + az)));
        const float nn = tanhf(fmaf(rr, an, i0n));
        const float hold = h[r_][uj];
        const float m = mkz[r_];
        const float hnew = (1.f - zz)*nn + zz*hold;
        const float hv = hnew*m + hold*(1.f - m);
        h[r_][uj] = hv;
        Hh[((size_t)st*BB + b0 + r_)*HH + uj] = hv;
      }
      {
        const int r_ = ur + 2;
        const float ar = part[0][r_][uj]+part[1][r_][uj]+part[2][r_][uj]+part[3][r_][uj] + br;
        const float az = part[0][r_][uj+HH]+part[1][r_][uj+HH]+part[2][r_][uj+HH]+part[3][r_][uj+HH] + bz;
        const float an = part[0][r_][uj+2*HH]+part[1][r_][uj+2*HH]+part[2][r_][uj+2*HH]+part[3][r_][uj+2*HH] + bn_;
        const float rr = 1.f/(1.f + __expf(-(i1r + ar)));
        const float zz = 1.f/(1.f + __expf(-(i1z + az)));
        const float nn = tanhf(fmaf(rr, an, i1n));
        const float hold = h[r_][uj];
        const float m = mkz[r_];
        const float hnew = (1.f - zz)*nn + zz*hold;
        const float hv = hnew*m + hold*(1.f - m);
        h[r_][uj] = hv;
        Hh[((size_t)st*BB + b0 + r_)*HH + uj] = hv;
      }
    }
    __syncthreads();
  }
  if (t < 512){
    hcar[(size_t)(b0+ur  )*HH + uj] = h[ur  ][uj];
    hcar[(size_t)(b0+ur+2)*HH + uj] = h[ur+2][uj];
  }
}

// ---------------------------------------------------------------------------
// Head (fused LN2): x=LN2(row); relu(x@nn1.T+b1) -> LN(8) -> @nn2.T+b2.
// ---------------------------------------------------------------------------
__global__ void head_ln_k(const float* __restrict__ hx,
                          const float* __restrict__ g2, const float* __restrict__ b2,
                          const float* __restrict__ w1, const float* __restrict__ b1,
                          const float* __restrict__ g3, const float* __restrict__ b3,
                          const float* __restrict__ w2, const float* __restrict__ b2h,
                          float* __restrict__ outp, long long r0){
  long long row = blockIdx.x;
  int t = threadIdx.x;
  float v = hx[row*HH + t];
  float s = v, q = v*v;
  #pragma unroll
  for (int o=32;o>0;o>>=1){ s += __shfl_down(s,o); q += __shfl_down(q,o); }
  __shared__ float ssm[4], qqm[4];
  int w = t >> 6;
  if ((t & 63) == 0){ ssm[w] = s; qqm[w] = q; }
  __syncthreads();
  if (t == 0){ ssm[0] = ssm[0]+ssm[1]+ssm[2]+ssm[3]; qqm[0] = qqm[0]+qqm[1]+qqm[2]+qqm[3]; }
  __syncthreads();
  s = ssm[0]; q = qqm[0];
  float mu  = s * (1.f/HH);
  float var = q * (1.f/HH) - mu*mu;
  float rs  = rsqrtf(var + EPSF);
  __shared__ float xs[HH];
  xs[t] = (v - mu)*rs*g2[t] + b2[t];
  __syncthreads();
  int o = t >> 5, l = t & 31;
  const float* wv = w1 + o*HH;
  float acc = 0.f;
  for (int k=l;k<HH;k+=32) acc = fmaf(xs[k], wv[k], acc);
  #pragma unroll
  for (int d=16;d>0;d>>=1) acc += __shfl_down(acc, d, 32);
  __shared__ float a8[8];
  if (l == 0) a8[o] = fmaxf(acc + b1[o], 0.f);
  __syncthreads();
  if (t == 0){
    float ss = 0.f;
    #pragma unroll
    for (int i=0;i<8;i++) ss += a8[i];
    float m8 = ss*0.125f;
    float qq = 0.f;
    #pragma unroll
    for (int i=0;i<8;i++){ float d = a8[i]-m8; qq = fmaf(d,d,qq); }
    float r8 = rsqrtf(qq*0.125f + EPSF);
    float y0 = b2h[0], y1 = b2h[1];
    #pragma unroll
    for (int i=0;i<8;i++){
      float vv = (a8[i]-m8)*r8*g3[i] + b3[i];
      y0 = fmaf(vv, w2[i],   y0);
      y1 = fmaf(vv, w2[8+i], y1);
    }
    outp[(r0+row)*2+0] = y0; outp[(r0+row)*2+1] = y1;
  }
}

// ---------------------------------------------------------------------------
// Host launcher — adaptive S-chunked pipeline (unchanged from R2).
// ---------------------------------------------------------------------------
extern "C" void kernel_launch(void* const* d_in, const int* in_sizes, int n_in,
                              void* d_out, int out_size, void* d_ws, size_t ws_size,
                              hipStream_t stream) {
  const float* X      = (const float*)d_in[0];
  const float* Mi     = (const float*)d_in[1];
  const float* mask   = (const float*)d_in[2];
  const float* i2h_w  = (const float*)d_in[3];
  const float* i2h_b  = (const float*)d_in[4];
  const float* comb_w = (const float*)d_in[5];
  const float* comb_b = (const float*)d_in[6];
  const float* down_w = (const float*)d_in[7];
  const float* down_b = (const float*)d_in[8];
  const float* conv1_w= (const float*)d_in[9];
  const float* conv1_b= (const float*)d_in[10];
  const float* conv2_w= (const float*)d_in[11];
  const float* conv2_b= (const float*)d_in[12];
  const float* bn1_g  = (const float*)d_in[13];
  const float* bn1_b  = (const float*)d_in[14];
  const float* bn2_g  = (const float*)d_in[15];
  const float* bn2_b  = (const float*)d_in[16];
  const float* r1_wih = (const float*)d_in[17];
  const float* r1_whh = (const float*)d_in[18];
  const float* r1_bih = (const float*)d_in[19];
  const float* r1_bhh = (const float*)d_in[20];
  const float* r1_cw  = (const float*)d_in[21];
  const float* r1_cb  = (const float*)d_in[22];
  const float* r2_wih = (const float*)d_in[23];
  const float* r2_whh = (const float*)d_in[24];
  const float* r2_bih = (const float*)d_in[25];
  const float* r2_bhh = (const float*)d_in[26];
  const float* r2_cw  = (const float*)d_in[27];
  const float* r2_cb  = (const float*)d_in[28];
  const float* ln1_g  = (const float*)d_in[29];
  const float* ln1_b  = (const float*)d_in[30];
  const float* ln2_g  = (const float*)d_in[31];
  const float* ln2_b  = (const float*)d_in[32];
  const float* ln3_g  = (const float*)d_in[33];
  const float* ln3_b  = (const float*)d_in[34];
  const float* nn1_w  = (const float*)d_in[35];
  const float* nn1_b  = (const float*)d_in[36];
  const float* nn2_w  = (const float*)d_in[37];
  const float* nn2_b  = (const float*)d_in[38];
  float* outp = (float*)d_out;

  // tail: H1C,H2C | PS,PQ | SCv,SHv | W1F,B1F | W2F,B2F | W1T,W2T | XcF
  const size_t tail_floats = 2*(size_t)BB*HH + 2*(size_t)256*HH + 2*HH
                           + (size_t)256*40 + 256 + (size_t)HH*HH + 256
                           + 2*(size_t)G3*HH + (size_t)SB*CC;
  // per-chunk: A + GIc + Cxp + Ee = 256+768+256+256 = 1536 floats/row
  int cands[6] = {256,128,64,32,16,8};
  int sc_chunk = 0;
  for (int ci=0; ci<6; ci++){
    size_t R = (size_t)512*cands[ci];
    size_t need = (R*1536 + tail_floats)*sizeof(float);
    if (need <= ws_size){ sc_chunk = cands[ci]; break; }
  }
  if (!sc_chunk) return;

  const size_t R = (size_t)512*sc_chunk;     // rows per chunk
  const int Ri = (int)R;
  const int nchunks = SB / Ri;

  float* wsf = (float*)d_ws;
  float* A   = wsf;                    // R*256
  float* GIc = A + R*HH;               // R*768
  float* Cxp = GIc + R*G3;             // R*256
  float* Ee  = Cxp + R*HH;             // R*256
  float* tl  = Ee + R*HH;
  float* H1C = tl;                     // BB*HH
  float* H2C = H1C + (size_t)BB*HH;
  float* PS  = H2C + (size_t)BB*HH;    // 256*HH
  float* PQ  = PS  + (size_t)256*HH;
  float* SCv = PQ  + (size_t)256*HH;   // HH
  float* SHv = SCv + HH;
  float* W1F = SHv + HH;               // 256*40
  float* B1F = W1F + (size_t)256*40;   // 256
  float* W2F = B1F + HH;               // 256*256
  float* B2F = W2F + (size_t)HH*HH;    // 256
  float* W1T = B2F + HH;               // 256*768 whhT (GRU1)
  float* W2T = W1T + (size_t)HH*G3;    // 256*768 whhT (GRU2)
  float* XcF = W2T + (size_t)HH*G3;    // SB*40 persisted comb output

  // one-time weight transposes for the scans
  whht_k<<<(G3*HH + 255)/256, 256, 0, stream>>>(r1_whh, W1T);
  whht_k<<<(G3*HH + 255)/256, 256, 0, stream>>>(r2_whh, W2T);

  const int PACKG = (Ri*80 + 255)/256;
  const int MB = Ri/128;

  // ---------- pass A: pack+comb once (persist Xc), BN1 stats ----------
  for (int c=0;c<nchunks;c++){
    long long r0 = (long long)c*R;
    pack_xm_chunk_k<<<PACKG, 256, 0, stream>>>(X, Mi, Ee, r0, Ri);
    gemm_tn<0><<<dim3(MB,1), 256, 0, stream>>>(Ee, 80, comb_w, 80, comb_b, XcF + r0*CC, CC, Ri, CC, 80);
    gemm_tn<0><<<dim3(MB,2), 256, 0, stream>>>(XcF + r0*CC, CC, conv1_w, CC, conv1_b, Ee, HH, Ri, HH, CC);
    bn_partial_k<<<Ri/512, 256, 0, stream>>>(Ee, PS, PQ, (int)(r0/512));
  }
  bn_final_k<<<1, 256, 0, stream>>>(PS, PQ, bn1_g, bn1_b, SCv, SHv);
  fold_k<<<(256*40 + 255)/256, 256, 0, stream>>>(conv1_w, conv1_b, SCv, SHv, W1F, B1F, 40);

  // ---------- pass B: BN2 stats (conv2 raw on folded-relu out1) ----------
  for (int c=0;c<nchunks;c++){
    long long r0 = (long long)c*R;
    gemm_tn<1><<<dim3(MB,2), 256, 0, stream>>>(XcF + r0*CC, CC, W1F, CC, B1F, Ee, HH, Ri, HH, CC);
    gemm_mf<0><<<dim3(MB,2), 256, 0, stream>>>(Ee, HH, conv2_w, HH, conv2_b, A, HH, HH, HH);
    bn_partial_k<<<Ri/512, 256, 0, stream>>>(A, PS, PQ, (int)(r0/512));
  }
  bn_final_k<<<1, 256, 0, stream>>>(PS, PQ, bn2_g, bn2_b, SCv, SHv);
  fold_k<<<(256*256 + 255)/256, 256, 0, stream>>>(conv2_w, conv2_b, SCv, SHv, W2F, B2F, 256);

  // ---------- h0 -> carries ----------
  h0_k<<<BB, HH, 0, stream>>>(X, i2h_w, i2h_b, H1C, H2C);

  // ---------- pass C: main pipeline ----------
  for (int c=0;c<nchunks;c++){
    long long r0 = (long long)c*R;
    // res = Xin @ down_w^T  (read X directly, lda=II, first 40 cols)
    gemm_tn<0><<<dim3(MB,2), 256, 0, stream>>>(X + r0*II, II, down_w, CC, down_b, A, HH, Ri, HH, CC);
    // out1r = relu(bn1-folded conv1(Xc))
    gemm_tn<1><<<dim3(MB,2), 256, 0, stream>>>(XcF + r0*CC, CC, W1F, CC, B1F, Ee, HH, Ri, HH, CC);
    // hx = bn2-folded conv2(out1r) + res
    gemm_mf<2><<<dim3(MB,2), 256, 0, stream>>>(Ee, HH, W2F, HH, B2F, A, HH, HH, HH);
    // GRU1
    gemm_mf<0><<<dim3(MB,6), 256, 0, stream>>>(A, HH, r1_wih, HH, r1_bih, GIc, G3, G3, HH);
    gru_scan_ks_k<<<BB/4, 768, 0, stream>>>(GIc, W1T, r1_bhh, mask + r0, H1C, Ee, sc_chunk);   // Hh1 -> Ee
    gemm_mf_dual<<<dim3(MB,2), 256, 0, stream>>>(A, Ee, r1_cw, r1_cb, Cxp, HH, HH);            // outs1 = [hx|Hh1]@cw^T
    ln_rows_k<<<Ri, 256, 0, stream>>>(Cxp, Ee, ln1_g, ln1_b);                                   // hx1 -> Ee
    // GRU2
    gemm_mf<0><<<dim3(MB,6), 256, 0, stream>>>(Ee, HH, r2_wih, HH, r2_bih, GIc, G3, G3, HH);
    gru_scan_ks_k<<<BB/4, 768, 0, stream>>>(GIc, W2T, r2_bhh, mask + r0, H2C, A, sc_chunk);    // Hh2 -> A
    gemm_mf_dual<<<dim3(MB,2), 256, 0, stream>>>(Ee, A, r2_cw, r2_cb, Cxp, HH, HH);            // outs2 = [hx1|Hh2]@cw^T
    // head (LN2 fused)
    head_ln_k<<<Ri, 256, 0, stream>>>(Cxp, ln2_g, ln2_b, nn1_w, nn1_b, ln3_g, ln3_b, nn2_w, nn2_b, outp, r0);
  }
}